// Round 7
// baseline (85.785 us; speedup 1.0000x reference)
//
#include <hip/hip_runtime.h>

// SeriesDecomp: x (32, 512, 2048) f32. Moving average K=2049, replicate pad p=1024.
// d_out = [x_s (N floats) | x_t (N floats)], x_t = movavg, x_s = x - x_t.
//
// Wave-per-row, zero LDS/barriers (R5 math), PLUS cross-row software pipeline:
// each wave owns 4 consecutive rows and prefetches row k+1's 8 dwordx4 loads
// before scanning/consuming row k, so the read stream + load latency overlap
// the scan chain and the write stream (steady mixed R/W instead of phase
// bursts). x is recomputed from chunk-scan differences to keep VGPR low.
//
// Lane i owns f4 chunks {i, i+64, ...}: float f = 256*j + 4*lane + d.
// The +-1024 partner of slot (j,d) is slot (j+-4,d) of the SAME lane:
//   f <  1024 (j<4):  wsum = (1024-f)*x[0] + E[j+4] + ls[j+4][d]
//   f >= 1024 (j>=4): wsum = (f-1023)*x[2047] + total - (E[j] (+ ls[j][d-1]))
// ls = per-chunk inclusive scan, E[j] = exclusive prefix of chunk (j,lane).

#define ROWLEN 2048
#define ROWS_PER_WAVE 4

typedef float f4 __attribute__((ext_vector_type(4)));

__global__ __launch_bounds__(256) void series_decomp_kernel(
    const float* __restrict__ x,
    float* __restrict__ xs_out,
    float* __restrict__ xt_out)
{
    const int lane = threadIdx.x & 63;
    const int wid  = threadIdx.x >> 6;
    const size_t g = (size_t)blockIdx.x * 4 + wid;   // global wave id
    const size_t row0 = g * ROWS_PER_WAVE;

    const f4* xin = reinterpret_cast<const f4*>(x);

    // Prefetch row 0.
    f4 v[8];
    {
        const size_t c0 = row0 * (ROWLEN / 4);
        #pragma unroll
        for (int j = 0; j < 8; ++j) v[j] = xin[c0 + 64 * j + lane];
    }

    #pragma unroll
    for (int k = 0; k < ROWS_PER_WAVE; ++k) {
        const size_t rowoff = (row0 + k) * ROWLEN;

        // Per-chunk inclusive scans (v dead afterwards; x recomputed from ls).
        f4 ls[8];
        #pragma unroll
        for (int j = 0; j < 8; ++j) {
            ls[j].x = v[j].x;
            ls[j].y = ls[j].x + v[j].y;
            ls[j].z = ls[j].y + v[j].z;
            ls[j].w = ls[j].z + v[j].w;
        }

        // Prefetch next row while this row's scan/consume proceeds.
        f4 vn[8];
        if (k + 1 < ROWS_PER_WAVE) {
            const size_t c1 = (row0 + k + 1) * (ROWLEN / 4);
            #pragma unroll
            for (int j = 0; j < 8; ++j) vn[j] = xin[c1 + 64 * j + lane];
        }

        // 8 wave shuffle-scans of chunk totals -> E[j], total.
        float E[8];
        float run = 0.0f;
        #pragma unroll
        for (int j = 0; j < 8; ++j) {
            const float T = ls[j].w;
            float W = T;
            #pragma unroll
            for (int d = 1; d < 64; d <<= 1) {
                const float o = __shfl_up(W, d, 64);
                if (lane >= d) W += o;
            }
            E[j] = run + (W - T);
            run += __shfl(W, 63, 64);
        }
        const float total = run;
        const float x0 = __shfl(ls[0].x, 0, 64);
        const float xl = __shfl(ls[7].w - ls[7].z, 63, 64);
        const float invK = 1.0f / 2049.0f;

        f4* xs4 = reinterpret_cast<f4*>(xs_out + rowoff);
        f4* xt4 = reinterpret_cast<f4*>(xt_out + rowoff);

        #pragma unroll
        for (int j = 0; j < 4; ++j) {
            // ---- slot j: floats fb..fb+3 < 1024 ----
            const int fb = 256 * j + 4 * lane;
            f4 xtA;
            xtA.x = ((float)(1024 - (fb + 0)) * x0 + (E[j + 4] + ls[j + 4].x)) * invK;
            xtA.y = ((float)(1024 - (fb + 1)) * x0 + (E[j + 4] + ls[j + 4].y)) * invK;
            xtA.z = ((float)(1024 - (fb + 2)) * x0 + (E[j + 4] + ls[j + 4].z)) * invK;
            xtA.w = ((float)(1024 - (fb + 3)) * x0 + (E[j + 4] + ls[j + 4].w)) * invK;
            f4 xA;
            xA.x = ls[j].x;
            xA.y = ls[j].y - ls[j].x;
            xA.z = ls[j].z - ls[j].y;
            xA.w = ls[j].w - ls[j].z;
            const f4 xsA = xA - xtA;
            xs4[64 * j + lane] = xsA;
            xt4[64 * j + lane] = xtA;

            // ---- slot j+4: floats f2..f2+3 >= 1024 ----
            const int f2 = 1024 + fb;
            f4 xtB;
            xtB.x = ((float)(f2 + 0 - 1023) * xl + (total -  E[j]))             * invK;
            xtB.y = ((float)(f2 + 1 - 1023) * xl + (total - (E[j] + ls[j].x))) * invK;
            xtB.z = ((float)(f2 + 2 - 1023) * xl + (total - (E[j] + ls[j].y))) * invK;
            xtB.w = ((float)(f2 + 3 - 1023) * xl + (total - (E[j] + ls[j].z))) * invK;
            f4 xB;
            xB.x = ls[j + 4].x;
            xB.y = ls[j + 4].y - ls[j + 4].x;
            xB.z = ls[j + 4].z - ls[j + 4].y;
            xB.w = ls[j + 4].w - ls[j + 4].z;
            const f4 xsB = xB - xtB;
            xs4[64 * (j + 4) + lane] = xsB;
            xt4[64 * (j + 4) + lane] = xtB;
        }

        if (k + 1 < ROWS_PER_WAVE) {
            #pragma unroll
            for (int j = 0; j < 8; ++j) v[j] = vn[j];
        }
    }
}

extern "C" void kernel_launch(void* const* d_in, const int* in_sizes, int n_in,
                              void* d_out, int out_size, void* d_ws, size_t ws_size,
                              hipStream_t stream) {
    const float* x = (const float*)d_in[0];
    const int n = in_sizes[0];               // 32*512*2048
    const int rows = n / ROWLEN;             // 16384
    const int blocks = rows / (4 * ROWS_PER_WAVE);   // 1024
    float* xs = (float*)d_out;               // output 0: seasonal
    float* xt = (float*)d_out + (size_t)n;   // output 1: trend
    series_decomp_kernel<<<blocks, 256, 0, stream>>>(x, xs, xt);
}

// Round 8
// 76.149 us; speedup vs baseline: 1.1265x; 1.1265x over previous
//
#include <hip/hip_runtime.h>

// SeriesDecomp: x (32, 512, 2048) f32. Moving average, K=2049, replicate pad p=1024.
// Outputs: x_s = x - x_t (first N elems of d_out), x_t = movavg (next N elems).
//
// Per row closed form via inclusive prefix sum pfx[] of the row:
//   window for output i covers padded positions [i, i+2048]
//   i <  1024: wsum = (1024-i)*x[0] + pfx[i+1024]
//   i >= 1024: wsum = (i-1023)*x[L-1] + (total - (i>1024 ? pfx[i-1025] : 0))
//   x_t[i] = wsum / 2049;  x_s[i] = x[i] - x_t[i]
//
// R8 = R1 restored verbatim: best of six structural variants (76.4 us vs
// 81-86 for vector-store / no-LDS / swizzled / pipelined rewrites). At the
// memory-system limit the winning levers are max occupancy (tiny blocks,
// low VGPR) + conflict-free scalar LDS consume; NT stores regress 40%
// (bypass L2 write combining).

#define ROWLEN 2048

__global__ __launch_bounds__(256) void series_decomp_kernel(
    const float* __restrict__ x,
    float* __restrict__ xs_out,
    float* __restrict__ xt_out)
{
    __shared__ float sx[ROWLEN];    // original row
    __shared__ float pfx[ROWLEN];   // inclusive prefix sums
    __shared__ float wsum4[4];      // per-wave totals

    const int t = threadIdx.x;
    const size_t rowoff = (size_t)blockIdx.x * ROWLEN;

    // Load 8 contiguous floats per thread (2x float4), stash row in LDS.
    const float4* xin = reinterpret_cast<const float4*>(x + rowoff);
    float4 a = xin[2 * t];
    float4 b = xin[2 * t + 1];
    reinterpret_cast<float4*>(sx)[2 * t]     = a;
    reinterpret_cast<float4*>(sx)[2 * t + 1] = b;

    // In-register inclusive scan of the 8 elements.
    float s[8];
    s[0] = a.x;
    s[1] = s[0] + a.y;
    s[2] = s[1] + a.z;
    s[3] = s[2] + a.w;
    s[4] = s[3] + b.x;
    s[5] = s[4] + b.y;
    s[6] = s[5] + b.z;
    s[7] = s[6] + b.w;
    const float tot = s[7];

    // Wave (64-lane) inclusive shuffle scan of per-thread totals.
    const int lane = t & 63;
    float sc = tot;
    #pragma unroll
    for (int d = 1; d < 64; d <<= 1) {
        float o = __shfl_up(sc, d, 64);
        if (lane >= d) sc += o;
    }
    const int wid = t >> 6;
    if (lane == 63) wsum4[wid] = sc;
    __syncthreads();

    // Exclusive prefix for this thread's first element.
    float base = sc - tot;
    #pragma unroll
    for (int w = 0; w < 3; ++w)
        if (w < wid) base += wsum4[w];

    // Publish full prefix array.
    float4 p0 = make_float4(base + s[0], base + s[1], base + s[2], base + s[3]);
    float4 p1 = make_float4(base + s[4], base + s[5], base + s[6], base + s[7]);
    reinterpret_cast<float4*>(pfx)[2 * t]     = p0;
    reinterpret_cast<float4*>(pfx)[2 * t + 1] = p1;
    __syncthreads();

    const float x0    = sx[0];
    const float xl    = sx[ROWLEN - 1];
    const float total = pfx[ROWLEN - 1];
    const float invK  = 1.0f / 2049.0f;

    float* xs_row = xs_out + rowoff;
    float* xt_row = xt_out + rowoff;

    // Stride-256 consume: LDS reads lane-consecutive (conflict-free),
    // global stores coalesced 4B/lane. Branch is wave-uniform per k.
    #pragma unroll
    for (int k = 0; k < 8; ++k) {
        const int i = t + 256 * k;
        float wsum;
        if (i < 1024) {
            wsum = (float)(1024 - i) * x0 + pfx[i + 1024];
        } else {
            const int j = i - 1025;
            float pm1 = pfx[j >= 0 ? j : 0];
            if (j < 0) pm1 = 0.0f;      // only i==1024 (t==0, k==4)
            wsum = (float)(i - 1023) * xl + (total - pm1);
        }
        const float xt = wsum * invK;
        xs_row[i] = sx[i] - xt;
        xt_row[i] = xt;
    }
}

extern "C" void kernel_launch(void* const* d_in, const int* in_sizes, int n_in,
                              void* d_out, int out_size, void* d_ws, size_t ws_size,
                              hipStream_t stream) {
    const float* x = (const float*)d_in[0];
    const int n = in_sizes[0];              // 32*512*2048
    const int rows = n / ROWLEN;            // 16384
    float* xs = (float*)d_out;              // output 0: seasonal
    float* xt = (float*)d_out + (size_t)n;  // output 1: trend
    series_decomp_kernel<<<rows, 256, 0, stream>>>(x, xs, xt);
}